// Round 1
// baseline (1202.068 us; speedup 1.0000x reference)
//
#include <hip/hip_runtime.h>

// WindowNonLocalDenoising on MI355X (gfx950).
// Fused single kernel: 1 block per 15x15 window (784 blocks), 512 threads (8 waves).
// All intermediates live in LDS as fp8-e4m3; MFMA is bf16 16x16x32 (HW-verified
// fragment layouts). proj_w is folded forward (z = proj@xw, out = z@S^T) so that
// every GEMM operand is stored [free][K] -> single xw layout, contiguous 8B frags.
//
// LDS map (bytes), total 162,568 <= 163,840:
//   XT  [225][264]  fp8  xw^T : XT[n][c] = x_window[c][n]      @      0 (59,400)
//   PT  [240][144]  fp8  phi^T: PT[m][e] = phi[e][m]           @ 59,400 (34,560)
//   Z   [256][240]  fp8  z[o][m] = sum_c proj[o][c] xw[c][m]   @ 93,960 (61,440)
//   TT  [ 16][144]  fp8  theta tile [n'][e]                    @155,400 ( 2,304)
//   ST  [ 16][240]  fp8  unnormalized exp tile [n'][m]         @157,704 ( 3,840)
//   RMAX/RSUM 8 waves x 16 rows f32                            @161,544 (2x 512)
// NOTE: A-frag reads for n/m-tile 14 touch "rows 225..239" of XT which overflow
// into PT -> garbage (possibly fp8-NaN). All such values flow only into (a) D
// rows n'>=225 (never stored) or (b) aff cols m>=225 (masked by INDEX to -1e30
// before any reduction) or (c) Z cols m>=225 (explicitly written 0). Safe.

#define WS_   15
#define B_    4
#define C_    256
#define H_    200
#define NHW   14
#define NWIN  (B_*NHW*NHW)   // 784
#define NPOS  225
#define E_    144

#define XT_OFF    0
#define XT_STRIDE 264        // 66 words ≡ 2 mod 32 -> conflict-free-ish frag reads
#define PT_OFF    59400
#define PT_STRIDE 144
#define Z_OFF     93960
#define Z_STRIDE  240
#define TT_OFF    155400
#define TT_STRIDE 144
#define ST_OFF    157704
#define ST_STRIDE 240
#define RMAX_OFF  161544
#define RSUM_OFF  162056
#define LDS_BYTES 162568

typedef __attribute__((ext_vector_type(2))) float  floatx2;
typedef __attribute__((ext_vector_type(4))) float  floatx4;
typedef __attribute__((ext_vector_type(8))) short  short8;

__device__ inline short bf16_trunc(float f) {   // exact for fp8-origin values
    return (short)(__float_as_uint(f) >> 16);
}
__device__ inline short bf16_rne(float f) {
    unsigned u = __float_as_uint(f);
    u += 0x7FFFu + ((u >> 16) & 1u);
    return (short)(u >> 16);
}
__device__ inline unsigned char to_fp8(float v) {
    int r = __builtin_amdgcn_cvt_pk_fp8_f32(v, v, 0, false);
    return (unsigned char)(r & 0xFF);
}
__device__ inline short8 zero8() {
    short8 z = {0,0,0,0,0,0,0,0};
    return z;
}
// 8 fp8 bytes (8B aligned in LDS) -> 8 bf16 fragment
__device__ inline short8 fp8frag(const char* p) {
    uint2 d = *(const uint2*)p;
    floatx2 f0 = __builtin_amdgcn_cvt_pk_f32_fp8((unsigned)d.x, false);
    floatx2 f1 = __builtin_amdgcn_cvt_pk_f32_fp8((unsigned)d.x, true);
    floatx2 f2 = __builtin_amdgcn_cvt_pk_f32_fp8((unsigned)d.y, false);
    floatx2 f3 = __builtin_amdgcn_cvt_pk_f32_fp8((unsigned)d.y, true);
    short8 r;
    r[0]=bf16_trunc(f0[0]); r[1]=bf16_trunc(f0[1]);
    r[2]=bf16_trunc(f1[0]); r[3]=bf16_trunc(f1[1]);
    r[4]=bf16_trunc(f2[0]); r[5]=bf16_trunc(f2[1]);
    r[6]=bf16_trunc(f3[0]); r[7]=bf16_trunc(f3[1]);
    return r;
}
// 8 consecutive f32 weights from global (16B aligned) -> 8 bf16 fragment
__device__ inline short8 wfrag(const float* p) {
    floatx4 a = *(const floatx4*)p;
    floatx4 b = *(const floatx4*)(p + 4);
    short8 r;
    r[0]=bf16_rne(a[0]); r[1]=bf16_rne(a[1]); r[2]=bf16_rne(a[2]); r[3]=bf16_rne(a[3]);
    r[4]=bf16_rne(b[0]); r[5]=bf16_rne(b[1]); r[6]=bf16_rne(b[2]); r[7]=bf16_rne(b[3]);
    return r;
}
#define MFMA(a,b,c) __builtin_amdgcn_mfma_f32_16x16x32_bf16((a),(b),(c),0,0,0)

__global__ __launch_bounds__(512) void wnl_kernel(
    const float* __restrict__ x, const float* __restrict__ theta_w,
    const float* __restrict__ phi_w, const float* __restrict__ proj_w,
    float* __restrict__ out)
{
    __shared__ char lds[LDS_BYTES];
    char* XT = lds + XT_OFF;
    char* PT = lds + PT_OFF;
    char* Zs = lds + Z_OFF;
    char* TT = lds + TT_OFF;
    char* ST = lds + ST_OFF;
    float* rmax = (float*)(lds + RMAX_OFF);
    float* rsum = (float*)(lds + RSUM_OFF);

    const int tid  = threadIdx.x;
    const int wv   = tid >> 6;
    const int lane = tid & 63;
    const int q    = lane >> 4;
    const int l16  = lane & 15;

    const int wid  = blockIdx.x;
    const int b    = wid / (NHW*NHW);
    const int rr   = wid % (NHW*NHW);
    const int ih   = rr / NHW;
    const int iw   = rr % NHW;
    const int row0 = ih * WS_;
    const int col0 = iw * WS_;

    const float* xb = x + (size_t)b * C_ * H_ * H_;

    // ---- Phase 0: gather window (reflect pad) -> XT fp8 [n][c] ----
    for (int idx = tid; idx < NPOS * C_; idx += 512) {
        int c  = idx / NPOS;
        int n  = idx - c * NPOS;          // consecutive tid -> consecutive n (coalesced-ish)
        int wr = row0 + n / WS_;
        int wc = col0 + n % WS_;
        int gr = (wr < H_) ? wr : (2*H_ - 2 - wr);
        int gc = (wc < H_) ? wc : (2*H_ - 2 - wc);
        float v = xb[((size_t)c * H_ + gr) * H_ + gc];
        XT[n * XT_STRIDE + c] = (char)to_fp8(v);
    }
    __syncthreads();

    // ---- Phase 1a: PT[m][e] = phi^T = (xw^T @ phi_w^T), tiles 15m x 9e ----
    for (int et = wv; et < 9; et += 8) {
        short8 bw[8];
        const float* wrow = phi_w + (et*16 + l16) * C_ + q*8;
        #pragma unroll
        for (int ck = 0; ck < 8; ++ck) bw[ck] = wfrag(wrow + ck*32);
        for (int mt = 0; mt < 15; ++mt) {
            floatx4 acc = {0.f,0.f,0.f,0.f};
            const char* arow = XT + (mt*16 + l16) * XT_STRIDE + q*8;
            #pragma unroll
            for (int ck = 0; ck < 8; ++ck)
                acc = MFMA(fp8frag(arow + ck*32), bw[ck], acc);
            #pragma unroll
            for (int r = 0; r < 4; ++r)
                PT[(mt*16 + q*4 + r) * PT_STRIDE + et*16 + l16] = (char)to_fp8(acc[r]);
        }
    }
    // ---- Phase 1b: Z[o][m] = proj_w @ xw, tiles 16o x 15m ----
    for (int ot = wv; ot < 16; ot += 8) {
        short8 aw[8];
        const float* wrow = proj_w + (ot*16 + l16) * C_ + q*8;
        #pragma unroll
        for (int ck = 0; ck < 8; ++ck) aw[ck] = wfrag(wrow + ck*32);
        for (int mt = 0; mt < 15; ++mt) {
            floatx4 acc = {0.f,0.f,0.f,0.f};
            const char* brow = XT + (mt*16 + l16) * XT_STRIDE + q*8;
            #pragma unroll
            for (int ck = 0; ck < 8; ++ck)
                acc = MFMA(aw[ck], fp8frag(brow + ck*32), acc);
            int m = mt*16 + l16;
            #pragma unroll
            for (int r = 0; r < 4; ++r) {
                float v = (m < NPOS) ? acc[r] : 0.f;   // zero pad cols: avoids 0*NaN later
                Zs[(ot*16 + q*4 + r) * Z_STRIDE + m] = (char)to_fp8(v);
            }
        }
    }
    __syncthreads();

    // ---- Phase 2: per n'-tile: theta tile -> aff -> softmax -> out ----
    for (int nt = 0; nt < 15; ++nt) {
        // (a) TT[n'][e] theta tile
        for (int et = wv; et < 9; et += 8) {
            short8 bw[8];
            const float* wrow = theta_w + (et*16 + l16) * C_ + q*8;
            #pragma unroll
            for (int ck = 0; ck < 8; ++ck) bw[ck] = wfrag(wrow + ck*32);
            floatx4 acc = {0.f,0.f,0.f,0.f};
            const char* arow = XT + (nt*16 + l16) * XT_STRIDE + q*8;
            #pragma unroll
            for (int ck = 0; ck < 8; ++ck)
                acc = MFMA(fp8frag(arow + ck*32), bw[ck], acc);
            #pragma unroll
            for (int r = 0; r < 4; ++r)
                TT[(q*4 + r) * TT_STRIDE + et*16 + l16] = (char)to_fp8(acc[r]);
        }
        __syncthreads();   // BAR1

        // (b) aff tiles: this wave owns m-tiles {wv, wv+8}
        short8 afr[5];
        {
            const char* arow = TT + l16 * TT_STRIDE + q*8;
            #pragma unroll
            for (int kk = 0; kk < 4; ++kk) afr[kk] = fp8frag(arow + kk*32);
            afr[4] = (q < 2) ? fp8frag(TT + l16 * TT_STRIDE + 128 + q*8) : zero8();
        }
        floatx4 aacc[2];
        const int nmt = (wv + 8 < 15) ? 2 : 1;
        for (int t = 0; t < nmt; ++t) {
            int mt = wv + 8*t;
            floatx4 acc = {0.f,0.f,0.f,0.f};
            const char* brow = PT + (mt*16 + l16) * PT_STRIDE + q*8;
            #pragma unroll
            for (int kk = 0; kk < 4; ++kk)
                acc = MFMA(afr[kk], fp8frag(brow + kk*32), acc);
            {
                short8 bf = (q < 2) ? fp8frag(PT + (mt*16 + l16)*PT_STRIDE + 128 + q*8)
                                    : zero8();
                acc = MFMA(afr[4], bf, acc);
            }
            int m = mt*16 + l16;
            if (m >= NPOS) { acc[0] = acc[1] = acc[2] = acc[3] = -1e30f; } // index mask kills pad/NaN
            aacc[t] = acc;
        }
        // per-wave row max (rows live on fixed quad; reduce over 16 lanes)
        #pragma unroll
        for (int r = 0; r < 4; ++r) {
            float v = aacc[0][r];
            if (nmt == 2) v = fmaxf(v, aacc[1][r]);
            #pragma unroll
            for (int off = 1; off < 16; off <<= 1) v = fmaxf(v, __shfl_xor(v, off));
            if (l16 == 0) rmax[wv*16 + q*4 + r] = v;
        }
        __syncthreads();   // BAR2
        float gmax[4];
        #pragma unroll
        for (int r = 0; r < 4; ++r) {
            float g = -3.4e38f;
            #pragma unroll
            for (int w2 = 0; w2 < 8; ++w2) g = fmaxf(g, rmax[w2*16 + q*4 + r]);
            gmax[r] = g;
        }
        float psum[4] = {0.f,0.f,0.f,0.f};
        for (int t = 0; t < nmt; ++t) {
            int mt = wv + 8*t;
            #pragma unroll
            for (int r = 0; r < 4; ++r) {
                float p = __expf((aacc[t][r] - gmax[r]) * (1.0f/12.0f)); // /sqrt(144)
                ST[(q*4 + r) * ST_STRIDE + mt*16 + l16] = (char)to_fp8(p);
                psum[r] += p;
            }
        }
        #pragma unroll
        for (int r = 0; r < 4; ++r) {
            float v = psum[r];
            #pragma unroll
            for (int off = 1; off < 16; off <<= 1) v += __shfl_xor(v, off);
            if (l16 == 0) rsum[wv*16 + q*4 + r] = v;
        }
        __syncthreads();   // BAR3

        // (c) out tile: out2[o][n'] = sum_m ST[n'][m] * Z[o][m]; normalize at write
        float ssum = 0.f;
        #pragma unroll
        for (int w2 = 0; w2 < 8; ++w2) ssum += rsum[w2*16 + l16];
        float sinv = 1.0f / ssum;
        short8 bfr[8];
        {
            const char* brow = ST + l16 * ST_STRIDE + q*8;
            #pragma unroll
            for (int km = 0; km < 7; ++km) bfr[km] = fp8frag(brow + km*32);
            bfr[7] = (q < 2) ? fp8frag(ST + l16 * ST_STRIDE + 224 + q*8) : zero8();
        }
        const int n  = nt*16 + l16;
        const int wr = row0 + n / WS_;
        const int wc = col0 + n % WS_;
        const bool valid = (n < NPOS) && (wr < H_) && (wc < H_);
        for (int ot = wv; ot < 16; ot += 8) {
            floatx4 acc = {0.f,0.f,0.f,0.f};
            const char* arow = Zs + (ot*16 + l16) * Z_STRIDE + q*8;
            #pragma unroll
            for (int km = 0; km < 7; ++km)
                acc = MFMA(fp8frag(arow + km*32), bfr[km], acc);
            {
                short8 af = (q < 2) ? fp8frag(Zs + (ot*16 + l16)*Z_STRIDE + 224 + q*8)
                                    : zero8();
                acc = MFMA(af, bfr[7], acc);
            }
            if (valid) {
                #pragma unroll
                for (int r = 0; r < 4; ++r) {
                    int o = ot*16 + q*4 + r;
                    size_t gi = (((size_t)b * C_ + o) * H_ + wr) * H_ + wc;
                    out[gi] = x[gi] + acc[r] * sinv;   // exact residual from global x
                }
            }
        }
        // no barrier needed here: next iter only writes TT (disjoint from (c) reads);
        // its BAR1 gates rmax/ST reuse.
    }
}

extern "C" void kernel_launch(void* const* d_in, const int* in_sizes, int n_in,
                              void* d_out, int out_size, void* d_ws, size_t ws_size,
                              hipStream_t stream) {
    (void)in_sizes; (void)n_in; (void)out_size; (void)d_ws; (void)ws_size;
    const float* x   = (const float*)d_in[0];
    const float* tw  = (const float*)d_in[1];
    const float* pw  = (const float*)d_in[2];
    const float* prw = (const float*)d_in[3];
    wnl_kernel<<<NWIN, 512, 0, stream>>>(x, tw, pw, prw, (float*)d_out);
}

// Round 2
// 753.992 us; speedup vs baseline: 1.5943x; 1.5943x over previous
//
#include <hip/hip_runtime.h>

// WindowNonLocalDenoising on MI355X (gfx950) — Round 2.
// 1 block per 15x15 window (784 blocks), 1024 threads (16 waves).
// All intermediates in LDS as fp8-e4m3, fed DIRECTLY to
// v_mfma_f32_16x16x32_fp8_fp8 (8 bytes/lane, same lane->k mapping as the
// bf16 16x16x32 shape verified in round 1). Weights are fp8-quantized with
// a x16 scale (folded into softmax scale 1/(12*256) and epilogue 1/(16*sum))
// to keep them out of e4m3 subnormal range.
//
// LDS map (bytes), total 163,592 <= 163,840:
//   XT  [225][264] fp8  xw^T : XT[n][c]                        @      0 (59,400)
//   PT  [240][144] fp8  16*phi^T  : PT[m][e]                   @ 59,400 (34,560)
//   Z   [256][240] fp8  16*proj@xw: Z[o][m]                    @ 93,960 (61,440)
//   TT  [ 16][144] fp8  16*theta tile [n'][e]                  @155,400 ( 2,304)
//   ST  [ 16][240] fp8  unnorm. exp tile [n'][m]               @157,704 ( 3,840)
//   RMAX/RSUM 16 waves x 16 rows f32                           @161,544 (2x1,024)
// Garbage rows (XT rows 225..239 overflow into PT region, possibly fp8-NaN)
// flow only into (a) D rows never stored, (b) aff cols m>=225 masked BY INDEX
// to -1e30, or (c) Z cols m>=225 explicitly zeroed. Safe.

#define WS_   15
#define B_    4
#define C_    256
#define H_    200
#define NHW   14
#define NWIN  (B_*NHW*NHW)   // 784
#define NPOS  225
#define E_    144
#define NWAVE 16

#define XT_STRIDE 264        // 66 dwords = 2 mod 32 -> conflict-free frag reads
#define PT_STRIDE 144
#define Z_STRIDE  240
#define TT_STRIDE 144
#define ST_STRIDE 240

#define XT_OFF    0
#define PT_OFF    59400
#define Z_OFF     93960
#define TT_OFF    155400
#define ST_OFF    157704
#define RMAX_OFF  161544
#define RSUM_OFF  162568
#define LDS_BYTES 163592

typedef __attribute__((ext_vector_type(4))) float floatx4;

__device__ inline unsigned char to_fp8(float v) {
    int r = __builtin_amdgcn_cvt_pk_fp8_f32(v, v, 0, false);
    return (unsigned char)(r & 0xFF);
}
// 8 consecutive f32 from global, scaled, -> 8 packed fp8 bytes (byte j = elem j)
__device__ inline long wfrag8(const float* p, float scale) {
    floatx4 a = *(const floatx4*)p;
    floatx4 b = *(const floatx4*)(p + 4);
    int lo = 0, hi = 0;
    lo = __builtin_amdgcn_cvt_pk_fp8_f32(a[0]*scale, a[1]*scale, lo, false);
    lo = __builtin_amdgcn_cvt_pk_fp8_f32(a[2]*scale, a[3]*scale, lo, true);
    hi = __builtin_amdgcn_cvt_pk_fp8_f32(b[0]*scale, b[1]*scale, hi, false);
    hi = __builtin_amdgcn_cvt_pk_fp8_f32(b[2]*scale, b[3]*scale, hi, true);
    return ((long)(unsigned)lo) | (((long)(unsigned)hi) << 32);
}
__device__ inline long ldsfrag(const char* p) { return *(const long*)p; }

#define MFMA8(a,b,c) __builtin_amdgcn_mfma_f32_16x16x32_fp8_fp8((a),(b),(c),0,0,0)

__global__ __launch_bounds__(1024) void wnl_kernel(
    const float* __restrict__ x, const float* __restrict__ theta_w,
    const float* __restrict__ phi_w, const float* __restrict__ proj_w,
    float* __restrict__ out)
{
    __shared__ char lds[LDS_BYTES];
    char* XT = lds + XT_OFF;
    char* PT = lds + PT_OFF;
    char* Zs = lds + Z_OFF;
    char* TT = lds + TT_OFF;
    char* ST = lds + ST_OFF;
    float* rmax = (float*)(lds + RMAX_OFF);
    float* rsum = (float*)(lds + RSUM_OFF);

    const int tid  = threadIdx.x;
    const int wv   = tid >> 6;          // 0..15
    const int lane = tid & 63;
    const int q    = lane >> 4;
    const int l16  = lane & 15;

    const int wid  = blockIdx.x;
    const int b    = wid / (NHW*NHW);
    const int rr   = wid % (NHW*NHW);
    const int ih   = rr / NHW;
    const int iw   = rr % NHW;
    const int row0 = ih * WS_;
    const int col0 = iw * WS_;

    const float* xb = x + (size_t)b * C_ * H_ * H_;

    // ---- Phase 0: gather window (reflect pad) -> XT fp8 [n][c] ----
    for (int idx = tid; idx < NPOS * C_; idx += 1024) {
        int c  = idx / NPOS;
        int n  = idx - c * NPOS;
        int wr = row0 + n / WS_;
        int wc = col0 + n % WS_;
        int gr = (wr < H_) ? wr : (2*H_ - 2 - wr);
        int gc = (wc < H_) ? wc : (2*H_ - 2 - wc);
        float v = xb[((size_t)c * H_ + gr) * H_ + gc];
        XT[n * XT_STRIDE + c] = (char)to_fp8(v);
    }
    __syncthreads();

    // ---- Phase 1 (merged): units 0..8 -> PT e-tiles; units 9..24 -> Z o-tiles ----
    for (int u = wv; u < 25; u += NWAVE) {
        if (u < 9) {
            // PT[m][e] = XT @ (16*phi)^T : A = XT rows (m), B = phi' rows (e)
            long bw[8];
            const float* wrow = phi_w + (u*16 + l16) * C_ + q*8;
            #pragma unroll
            for (int ck = 0; ck < 8; ++ck) bw[ck] = wfrag8(wrow + ck*32, 16.f);
            for (int mt = 0; mt < 15; ++mt) {
                floatx4 acc = {0.f,0.f,0.f,0.f};
                const char* arow = XT + (mt*16 + l16) * XT_STRIDE + q*8;
                #pragma unroll
                for (int ck = 0; ck < 8; ++ck)
                    acc = MFMA8(ldsfrag(arow + ck*32), bw[ck], acc);
                #pragma unroll
                for (int r = 0; r < 4; ++r)
                    PT[(mt*16 + q*4 + r) * PT_STRIDE + u*16 + l16] = (char)to_fp8(acc[r]);
            }
        } else {
            // Z[o][m] = (16*proj) @ xw : A = proj' rows (o), B = XT rows (m)
            int ot = u - 9;
            long aw[8];
            const float* wrow = proj_w + (ot*16 + l16) * C_ + q*8;
            #pragma unroll
            for (int ck = 0; ck < 8; ++ck) aw[ck] = wfrag8(wrow + ck*32, 16.f);
            for (int mt = 0; mt < 15; ++mt) {
                floatx4 acc = {0.f,0.f,0.f,0.f};
                const char* brow = XT + (mt*16 + l16) * XT_STRIDE + q*8;
                #pragma unroll
                for (int ck = 0; ck < 8; ++ck)
                    acc = MFMA8(aw[ck], ldsfrag(brow + ck*32), acc);
                int m = mt*16 + l16;
                #pragma unroll
                for (int r = 0; r < 4; ++r) {
                    float v = (m < NPOS) ? acc[r] : 0.f;  // zero pad cols: no 0*NaN later
                    Zs[(ot*16 + q*4 + r) * Z_STRIDE + m] = (char)to_fp8(v);
                }
            }
        }
    }

    // Persistent theta' weight frags for waves 0..8 (hoisted out of nt loop)
    long thw[8];
    if (wv < 9) {
        const float* wrow = theta_w + (wv*16 + l16) * C_ + q*8;
        #pragma unroll
        for (int ck = 0; ck < 8; ++ck) thw[ck] = wfrag8(wrow + ck*32, 16.f);
    }
    __syncthreads();

    // ---- Phase 2: per n'-tile: theta tile -> aff -> softmax -> out ----
    for (int nt = 0; nt < 15; ++nt) {
        // (a) TT[n'][e] = 16*theta tile (waves 0..8, one e-tile each)
        if (wv < 9) {
            floatx4 acc = {0.f,0.f,0.f,0.f};
            const char* arow = XT + (nt*16 + l16) * XT_STRIDE + q*8;
            #pragma unroll
            for (int ck = 0; ck < 8; ++ck)
                acc = MFMA8(ldsfrag(arow + ck*32), thw[ck], acc);
            #pragma unroll
            for (int r = 0; r < 4; ++r)
                TT[(q*4 + r) * TT_STRIDE + wv*16 + l16] = (char)to_fp8(acc[r]);
        }
        __syncthreads();   // BAR1

        // (b) aff tile: wave wv owns m-tile wv (waves 0..14)
        long afr[5];
        {
            const char* arow = TT + l16 * TT_STRIDE + q*8;
            #pragma unroll
            for (int kk = 0; kk < 4; ++kk) afr[kk] = ldsfrag(arow + kk*32);
            afr[4] = (q < 2) ? ldsfrag(TT + l16 * TT_STRIDE + 128 + q*8) : 0L;
        }
        floatx4 aacc = {0.f,0.f,0.f,0.f};
        if (wv < 15) {
            const char* brow = PT + (wv*16 + l16) * PT_STRIDE + q*8;
            #pragma unroll
            for (int kk = 0; kk < 4; ++kk)
                aacc = MFMA8(afr[kk], ldsfrag(brow + kk*32), aacc);
            long bf = (q < 2) ? ldsfrag(PT + (wv*16 + l16)*PT_STRIDE + 128 + q*8) : 0L;
            aacc = MFMA8(afr[4], bf, aacc);
            int m = wv*16 + l16;
            if (m >= NPOS) { aacc[0]=aacc[1]=aacc[2]=aacc[3] = -1e30f; } // index mask
            #pragma unroll
            for (int r = 0; r < 4; ++r) {
                float v = aacc[r];
                #pragma unroll
                for (int off = 1; off < 16; off <<= 1) v = fmaxf(v, __shfl_xor(v, off));
                if (l16 == 0) rmax[wv*16 + q*4 + r] = v;
            }
        }
        __syncthreads();   // BAR2
        // global row max over the 15 active waves; exp; partial sums
        float psum[4] = {0.f,0.f,0.f,0.f};
        if (wv < 15) {
            float gmax[4];
            #pragma unroll
            for (int r = 0; r < 4; ++r) {
                float g = -3.4e38f;
                #pragma unroll
                for (int w2 = 0; w2 < 15; ++w2) g = fmaxf(g, rmax[w2*16 + q*4 + r]);
                gmax[r] = g;
            }
            #pragma unroll
            for (int r = 0; r < 4; ++r) {
                // aff' = 256*aff_true -> logits scale 1/(12*256)
                float p = __expf((aacc[r] - gmax[r]) * (1.0f/3072.0f));
                ST[(q*4 + r) * ST_STRIDE + wv*16 + l16] = (char)to_fp8(p);
                psum[r] += p;
            }
            #pragma unroll
            for (int r = 0; r < 4; ++r) {
                float v = psum[r];
                #pragma unroll
                for (int off = 1; off < 16; off <<= 1) v += __shfl_xor(v, off);
                if (l16 == 0) rsum[wv*16 + q*4 + r] = v;
            }
        }
        __syncthreads();   // BAR3

        // (c) out tile: D[o][n'] = sum_m Z'[o][m] * ST[n'][m]; wave wv owns o-tile wv
        float ssum = 0.f;
        #pragma unroll
        for (int w2 = 0; w2 < 15; ++w2) ssum += rsum[w2*16 + l16];
        float sinv = 1.0f / (16.0f * ssum);   // undo proj x16 scale + normalize
        long bfr[8];
        {
            const char* brow = ST + l16 * ST_STRIDE + q*8;
            #pragma unroll
            for (int km = 0; km < 7; ++km) bfr[km] = ldsfrag(brow + km*32);
            bfr[7] = (q < 2) ? ldsfrag(ST + l16 * ST_STRIDE + 224 + q*8) : 0L;
        }
        const int n  = nt*16 + l16;
        const int wr = row0 + n / WS_;
        const int wc = col0 + n % WS_;
        const bool valid = (n < NPOS) && (wr < H_) && (wc < H_);
        {
            floatx4 acc = {0.f,0.f,0.f,0.f};
            const char* arow = Zs + (wv*16 + l16) * Z_STRIDE + q*8;
            #pragma unroll
            for (int km = 0; km < 7; ++km)
                acc = MFMA8(ldsfrag(arow + km*32), bfr[km], acc);
            long af = (q < 2) ? ldsfrag(Zs + (wv*16 + l16)*Z_STRIDE + 224 + q*8) : 0L;
            acc = MFMA8(af, bfr[7], acc);
            if (valid) {
                #pragma unroll
                for (int r = 0; r < 4; ++r) {
                    int o = wv*16 + q*4 + r;
                    size_t gi = (((size_t)b * C_ + o) * H_ + wr) * H_ + wc;
                    out[gi] = x[gi] + acc[r] * sinv;   // exact residual from global x
                }
            }
        }
        // next iter's TT write is gated by its BAR1; ST/rmax/rsum reuse likewise.
    }
}

extern "C" void kernel_launch(void* const* d_in, const int* in_sizes, int n_in,
                              void* d_out, int out_size, void* d_ws, size_t ws_size,
                              hipStream_t stream) {
    (void)in_sizes; (void)n_in; (void)out_size; (void)d_ws; (void)ws_size;
    const float* x   = (const float*)d_in[0];
    const float* tw  = (const float*)d_in[1];
    const float* pw  = (const float*)d_in[2];
    const float* prw = (const float*)d_in[3];
    wnl_kernel<<<NWIN, 1024, 0, stream>>>(x, tw, pw, prw, (float*)d_out);
}